// Round 2
// baseline (23858.621 us; speedup 1.0000x reference)
//
#include <hip/hip_runtime.h>
#include <stdint.h>

#define NTOT   131072
#define NSTEP  60
#define MBLK   64
#define WPITCH 132   // u32 words per W-slab row
#define APITCH 132   // halves per ACT-plane row / floats per V1f row

// LDS layout (bytes)
#define OFF_SLAB 0                        // 128*132*4 = 67584
#define OFF_ACTH 67584                    // 64*132*2  = 16896
#define OFF_ACTL 84480                    // 16896  (ACTH+ACTL overlaid by V1f fp32 64*132*4)
#define OFF_W1C  101376                   // 128*16 = 2048
#define OFF_B2   103424
#define OFF_B3   103936
#define OFF_B4   104448
#define OFF_W5   104960
#define OFF_XB   105472                   // 128*4 = 512
#define LDS_TOTAL 105984

typedef float  f32x4  __attribute__((ext_vector_type(4)));
typedef short  bf16x8 __attribute__((ext_vector_type(8)));

union FragU { bf16x8 v; uint32_t u[4]; uint16_t h[8]; };

static __device__ __forceinline__ uint16_t f2bf(float f) {
  uint32_t u = __float_as_uint(f);
  u += 0x7fffu + ((u >> 16) & 1u);        // round-to-nearest-even
  return (uint16_t)(u >> 16);
}
static __device__ __forceinline__ float bf2f(uint16_t h) {
  return __uint_as_float(((uint32_t)h) << 16);
}
static __device__ __forceinline__ float sigm(float z) {
  return 1.0f / (1.0f + expf(-z));        // precise expf (~1 ulp), not __expf
}
// split v into hi+lo bf16 (bf16 exponent range == fp32 -> lo never subnormal)
static __device__ __forceinline__ void split2(float v, uint16_t& hi, uint16_t& lo) {
  hi = f2bf(v);
  lo = f2bf(v - bf2f(hi));
}

extern "C" __global__ void __launch_bounds__(512, 2)
ebm_mcmc_kernel(const float* __restrict__ x0, const float* __restrict__ w1,
                const float* __restrict__ b1, const float* __restrict__ w2,
                const float* __restrict__ b2, const float* __restrict__ w3,
                const float* __restrict__ b3, const float* __restrict__ w4,
                const float* __restrict__ b4, const float* __restrict__ w5,
                const float* __restrict__ noise, float* __restrict__ out)
{
  extern __shared__ char smem[];
  uint32_t* SLAB = (uint32_t*)(smem + OFF_SLAB);   // current W matrix, [out][in], u32 = hi<<16|lo
  uint16_t* ACTH = (uint16_t*)(smem + OFF_ACTH);   // activation hi plane [sample][hidden]
  uint16_t* ACTL = (uint16_t*)(smem + OFF_ACTL);   // activation lo plane
  float*    V1F  = (float*)(smem + OFF_ACTH);      // fp32 v1 overlay [sample][APITCH]
  f32x4*    W1C  = (f32x4*)(smem + OFF_W1C);       // (w1[0][n], w1[1][n], b1[n], 0)
  float*    B2s  = (float*)(smem + OFF_B2);
  float*    B3s  = (float*)(smem + OFF_B3);
  float*    B4s  = (float*)(smem + OFF_B4);
  float*    W5s  = (float*)(smem + OFF_W5);
  float*    XB   = (float*)(smem + OFF_XB);        // x state fp32 [64][2]

  const int t   = threadIdx.x;
  const int blk = blockIdx.x;

  // ---- stage one weight matrix into slab as packed hi|lo bf16 ----
  auto stage_w = [&](const float* __restrict__ w) {
#pragma unroll
    for (int k = 0; k < 32; ++k) {
      int idx = t + k * 512;
      int b = idx >> 7, a = idx & 127;       // b = input row of W, a = output col
      float v = w[idx];
      uint16_t hi, lo; split2(v, hi, lo);
      SLAB[a * WPITCH + b] = ((uint32_t)hi << 16) | lo;   // W^T storage: [out][in]
    }
  };

  // ---- constants + x init ----
  if (t < 128) {
    f32x4 v; v.x = w1[t]; v.y = w1[128 + t]; v.z = b1[t]; v.w = 0.0f;
    W1C[t] = v;
    B2s[t] = b2[t]; B3s[t] = b3[t]; B4s[t] = b4[t]; W5s[t] = w5[t];
    XB[t] = x0[blk * 128 + t];
  }
  stage_w(w2);
  __syncthreads();

  const int lane = t & 63;
  const int wave = t >> 6;
  const int c = lane & 15;          // sample-within-tile / A-row index
  const int q = lane >> 4;          // quad
  const int SR = wave & 1;          // hidden half (64*SR)
  const int SC = wave >> 1;         // sample 16-group (16*SC)
  const int ms = 16 * SC + c;       // this lane's sample row

  f32x4 acc[4];
  f32x4 D1[4], D2[4], D3[4];        // silu' kept in fp32 (round-1 leak fixed)

  auto unpackPair = [&](const uint32_t* x, FragU& Ah, FragU& Al) {
#pragma unroll
    for (int i = 0; i < 4; ++i) {
      uint32_t e0 = x[2 * i], e1 = x[2 * i + 1];
      Ah.u[i] = (e0 >> 16) | (e1 & 0xFFFF0000u);
      Al.u[i] = (e0 & 0xFFFFu) | (e1 << 16);
    }
  };
  auto loadApair = [&](int TR, int kk, FragU& Ah, FragU& Al) {   // fwd: W^T row-contig
    int row = 64 * SR + 16 * TR + c;
    const uint32_t* p = SLAB + row * WPITCH + kk * 32 + q * 8;
    uint32_t x[8];
    *(uint4*)&x[0] = *(const uint4*)p;
    *(uint4*)&x[4] = *(const uint4*)(p + 4);
    unpackPair(x, Ah, Al);
  };
  auto loadAgather = [&](int TR, int kk, FragU& Ah, FragU& Al) { // bwd: column gather
    int colb = 64 * SR + 16 * TR + c;
    const uint32_t* p = SLAB + (kk * 32 + q * 8) * WPITCH + colb;
    uint32_t x[8];
#pragma unroll
    for (int j = 0; j < 8; ++j) x[j] = p[j * WPITCH];
    unpackPair(x, Ah, Al);
  };
  auto loadBpair = [&](int kk, FragU& Bh, FragU& Bl) {           // ACT planes
    int off = ms * APITCH + kk * 32 + q * 8;
    uint2 a0 = *(const uint2*)(ACTH + off);
    uint2 a1 = *(const uint2*)(ACTH + off + 4);
    Bh.u[0] = a0.x; Bh.u[1] = a0.y; Bh.u[2] = a1.x; Bh.u[3] = a1.y;
    uint2 b0 = *(const uint2*)(ACTL + off);
    uint2 b1v = *(const uint2*)(ACTL + off + 4);
    Bl.u[0] = b0.x; Bl.u[1] = b0.y; Bl.u[2] = b1v.x; Bl.u[3] = b1v.y;
  };

  auto gemm = [&](bool bwd) {
#pragma unroll
    for (int i = 0; i < 4; ++i) acc[i] = (f32x4){0.f, 0.f, 0.f, 0.f};
#pragma unroll
    for (int kk = 0; kk < 4; ++kk) {
      FragU Bh, Bl; loadBpair(kk, Bh, Bl);
#pragma unroll
      for (int TR = 0; TR < 4; ++TR) {
        FragU Ah, Al;
        if (bwd) loadAgather(TR, kk, Ah, Al);
        else     loadApair(TR, kk, Ah, Al);
        acc[TR] = __builtin_amdgcn_mfma_f32_16x16x32_bf16(Ah.v, Bh.v, acc[TR], 0, 0, 0);
        acc[TR] = __builtin_amdgcn_mfma_f32_16x16x32_bf16(Ah.v, Bl.v, acc[TR], 0, 0, 0);
        acc[TR] = __builtin_amdgcn_mfma_f32_16x16x32_bf16(Al.v, Bh.v, acc[TR], 0, 0, 0);
      }
    }
  };

  auto storeSplit4 = [&](int n0, float v0, float v1, float v2, float v3) {
    uint16_t h0,l0,h1,l1,h2,l2,h3,l3;
    split2(v0,h0,l0); split2(v1,h1,l1); split2(v2,h2,l2); split2(v3,h3,l3);
    *(uint2*)(ACTH + ms * APITCH + n0) =
        make_uint2((uint32_t)h0 | ((uint32_t)h1 << 16), (uint32_t)h2 | ((uint32_t)h3 << 16));
    *(uint2*)(ACTL + ms * APITCH + n0) =
        make_uint2((uint32_t)l0 | ((uint32_t)l1 << 16), (uint32_t)l2 | ((uint32_t)l3 << 16));
  };

  // z = acc + b ; h=silu(z) split-> ACT ; D=silu'(z) fp32 regs
  auto ep_fwd = [&](const float* Bs, f32x4 (&D)[4]) {
#pragma unroll
    for (int TR = 0; TR < 4; ++TR) {
      int n0 = 64 * SR + 16 * TR + 4 * q;
      f32x4 bv = *(const f32x4*)(Bs + n0);
      float h[4];
#pragma unroll
      for (int r = 0; r < 4; ++r) {
        float z = acc[TR][r] + bv[r];
        float s = sigm(z);
        float hh = z * s;
        D[TR][r] = s * (1.0f + z - hh);
        h[r] = hh;
      }
      storeSplit4(n0, h[0], h[1], h[2], h[3]);
    }
  };

  // v4 = w5[n] * silu'(acc + b4) -> ACT split
  auto ep_v4 = [&]() {
#pragma unroll
    for (int TR = 0; TR < 4; ++TR) {
      int n0 = 64 * SR + 16 * TR + 4 * q;
      f32x4 bv = *(const f32x4*)(B4s + n0);
      f32x4 wv = *(const f32x4*)(W5s + n0);
      float v[4];
#pragma unroll
      for (int r = 0; r < 4; ++r) {
        float z = acc[TR][r] + bv[r];
        float s = sigm(z);
        float d = s * (1.0f + z - z * s);
        v[r] = wv[r] * d;
      }
      storeSplit4(n0, v[0], v[1], v[2], v[3]);
    }
  };

  // v = u .* D -> ACT split
  auto ep_bwd = [&](f32x4 (&D)[4]) {
#pragma unroll
    for (int TR = 0; TR < 4; ++TR) {
      int n0 = 64 * SR + 16 * TR + 4 * q;
      storeSplit4(n0, acc[TR][0] * D[TR][0], acc[TR][1] * D[TR][1],
                      acc[TR][2] * D[TR][2], acc[TR][3] * D[TR][3]);
    }
  };

  // v1 = u .* D1 -> fp32 overlay (g-path stays fp32)
  auto ep_bwd1 = [&]() {
#pragma unroll
    for (int TR = 0; TR < 4; ++TR) {
      int n0 = 64 * SR + 16 * TR + 4 * q;
      f32x4 v;
#pragma unroll
      for (int r = 0; r < 4; ++r) v[r] = acc[TR][r] * D1[TR][r];
      *(f32x4*)(V1F + ms * APITCH + n0) = v;
    }
  };

  // layer 1 (K=2) fp32 VALU: h1 split -> ACT, D1 fp32 regs
  auto l1_phase = [&]() {
    float xa = XB[2 * ms], xb = XB[2 * ms + 1];
#pragma unroll
    for (int TR = 0; TR < 4; ++TR) {
      int n0 = 64 * SR + 16 * TR + 4 * q;
      float h[4];
#pragma unroll
      for (int r = 0; r < 4; ++r) {
        f32x4 wv = W1C[n0 + r];
        float z = xa * wv.x + xb * wv.y + wv.z;
        float s = sigm(z);
        float hh = z * s;
        D1[TR][r] = s * (1.0f + z - hh);
        h[r] = hh;
      }
      storeSplit4(n0, h[0], h[1], h[2], h[3]);
    }
  };

  // g = clip(v1 @ W1^T) fp32 ; Langevin update
  auto g_phase = [&](int step) {
    if (t < 128) {
      int s = t >> 1, p = t & 1;
      float g0 = 0.f, g1 = 0.f;
      const f32x4* vp = (const f32x4*)(V1F + s * APITCH + 64 * p);
#pragma unroll
      for (int i = 0; i < 16; ++i) {
        f32x4 v = vp[i];
        int n = 64 * p + 4 * i;
#pragma unroll
        for (int r = 0; r < 4; ++r) {
          f32x4 wv = W1C[n + r];
          g0 += v[r] * wv.x;
          g1 += v[r] * wv.y;
        }
      }
      g0 += __shfl_xor(g0, 1);
      g1 += __shfl_xor(g1, 1);
      float g = p ? g1 : g0;
      g = fminf(fmaxf(g, -0.03f), 0.03f);
      float epsv = 10.0f * (1.0f - (float)step / 60.0f);
      int gm = blk * MBLK + s;
      float nz = noise[(size_t)((step * NTOT + gm) * 2 + p)];
      float xn = XB[t] + sqrtf(2.0f * epsv) * nz * 0.005f + epsv * g;
      xn = fminf(fmaxf(xn, -2.43f), 3.05f);
      XB[t] = xn;
      if (step == NSTEP - 1) out[(size_t)gm * 2 + p] = xn;
    }
  };

#pragma unroll 1
  for (int step = 0; step < NSTEP; ++step) {
    l1_phase();                      __syncthreads();
    gemm(false);                     __syncthreads();   // z2 = W2^T . h1   (slab=W2)
    stage_w(w3); ep_fwd(B2s, D2);    __syncthreads();
    gemm(false);                     __syncthreads();   // z3 = W3^T . h2
    stage_w(w4); ep_fwd(B3s, D3);    __syncthreads();
    gemm(false);                     __syncthreads();   // z4 = W4^T . h3
    ep_v4();                         __syncthreads();
    gemm(true);                      __syncthreads();   // u3 = v4 @ W4^T   (slab=W4)
    stage_w(w3); ep_bwd(D3);         __syncthreads();
    gemm(true);                      __syncthreads();   // u2 = v3 @ W3^T
    stage_w(w2); ep_bwd(D2);         __syncthreads();
    gemm(true);                      __syncthreads();   // u1 = v2 @ W2^T
    ep_bwd1();                       __syncthreads();   // v1 fp32
    g_phase(step);                   __syncthreads();   // slab=W2 ready for next step
  }
}

extern "C" void kernel_launch(void* const* d_in, const int* in_sizes, int n_in,
                              void* d_out, int out_size, void* d_ws, size_t ws_size,
                              hipStream_t stream) {
  // inputs: x0,w1,b1,w2,b2,w3,b3,w4,b4,w5,b5,noise  (b5 unused by the gradient)
  (void)in_sizes; (void)n_in; (void)out_size; (void)d_ws; (void)ws_size;
  hipFuncSetAttribute((const void*)ebm_mcmc_kernel,
                      hipFuncAttributeMaxDynamicSharedMemorySize, LDS_TOTAL);
  ebm_mcmc_kernel<<<NTOT / MBLK, 512, LDS_TOTAL, stream>>>(
      (const float*)d_in[0], (const float*)d_in[1], (const float*)d_in[2],
      (const float*)d_in[3], (const float*)d_in[4], (const float*)d_in[5],
      (const float*)d_in[6], (const float*)d_in[7], (const float*)d_in[8],
      (const float*)d_in[9], (const float*)d_in[11], (float*)d_out);
}

// Round 3
// 8539.190 us; speedup vs baseline: 2.7940x; 2.7940x over previous
//
#include <hip/hip_runtime.h>
#include <stdint.h>

#define NTOT   131072
#define NSTEP  60
#define MBLK   64
#define PITW   136          // halves per row (both W slab and ACT planes)
#define WPLANE 17408        // halves per W plane (128*136)
#define APLANE 8704         // halves per ACT plane (64*136)
#define MAT_B  69632        // bytes per matrix image (hi+lo planes)

// LDS byte offsets
#define OFF_SLAB 0                   // 69632 (hi plane, then lo plane)
#define OFF_ACTH 69632               // 17408
#define OFF_V1F  69632               // fp32 overlay 64*132*4 = 33792 (aliases ACT, phase-disjoint)
#define OFF_W1C  104448              // 2048
#define OFF_B2   106496
#define OFF_B3   107008
#define OFF_B4   107520
#define OFF_W5   108032
#define OFF_XB   108544              // 512
#define LDS_TOTAL 109056

typedef float  f32x4  __attribute__((ext_vector_type(4)));
typedef short  bf16x8 __attribute__((ext_vector_type(8)));
union FragU { bf16x8 v; uint32_t u[4]; uint16_t h[8]; };

static __device__ __forceinline__ uint16_t f2bf_rne(float f) {
  uint32_t u = __float_as_uint(f);
  u += 0x7fffu + ((u >> 16) & 1u);
  return (uint16_t)(u >> 16);
}
static __device__ __forceinline__ float bf2f(uint16_t h) {
  return __uint_as_float(((uint32_t)h) << 16);
}
static __device__ __forceinline__ float fsigm(float z) {
#if __has_builtin(__builtin_amdgcn_exp2f) && __has_builtin(__builtin_amdgcn_rcpf)
  return __builtin_amdgcn_rcpf(1.0f + __builtin_amdgcn_exp2f(z * -1.44269504089f));
#else
  return 1.0f / (1.0f + __expf(-z));
#endif
}
// (bf16_trunc(a)) | (bf16_trunc(b) << 16) via one v_perm_b32
static __device__ __forceinline__ uint32_t packhi(float a, float b) {
  return __builtin_amdgcn_perm(__float_as_uint(b), __float_as_uint(a), 0x07060302u);
}
static __device__ __forceinline__ float cutf(float v) {
  return __uint_as_float(__float_as_uint(v) & 0xffff0000u);
}

// ---- pre-kernel: build swizzled split-bf16 LDS images of W2,W3,W4 in d_ws ----
extern "C" __global__ void ebm_prep_kernel(const float* __restrict__ w2,
                                           const float* __restrict__ w3,
                                           const float* __restrict__ w4,
                                           uint16_t* __restrict__ ws) {
  const float* w = (blockIdx.x == 0) ? w2 : (blockIdx.x == 1) ? w3 : w4;
  uint16_t* hiP = ws + (size_t)blockIdx.x * (MAT_B / 2);
  uint16_t* loP = hiP + WPLANE;
  for (int e = threadIdx.x; e < 16384; e += blockDim.x) {
    int i = e >> 7, o = e & 127;            // w is [in i][out o]
    float v = w[e];
    uint16_t h = f2bf_rne(v);
    uint16_t l = f2bf_rne(v - bf2f(h));
    int off = o * PITW + (i ^ (((o >> 3) & 3) << 4));
    hiP[off] = h; loP[off] = l;
  }
}

extern "C" __global__ void __launch_bounds__(512, 2)
ebm_mcmc_kernel(const float* __restrict__ x0, const float* __restrict__ w1,
                const float* __restrict__ b1, const float* __restrict__ b2,
                const float* __restrict__ b3, const float* __restrict__ b4,
                const float* __restrict__ w5, const float* __restrict__ noise,
                const uint16_t* __restrict__ wsW, float* __restrict__ out)
{
  extern __shared__ char smem[];
  uint16_t* SLABH = (uint16_t*)(smem + OFF_SLAB);   // lo plane at +WPLANE halves
  uint16_t* ACTH  = (uint16_t*)(smem + OFF_ACTH);   // lo plane at +APLANE halves
  float*    V1F   = (float*)(smem + OFF_V1F);
  f32x4*    W1C   = (f32x4*)(smem + OFF_W1C);       // (w1[0][n], w1[1][n], b1[n], 0)
  float*    B2s   = (float*)(smem + OFF_B2);
  float*    B3s   = (float*)(smem + OFF_B3);
  float*    B4s   = (float*)(smem + OFF_B4);
  float*    W5s   = (float*)(smem + OFF_W5);
  float*    XB    = (float*)(smem + OFF_XB);

  const int t   = threadIdx.x;
  const int blk = blockIdx.x;

  // ---- async restage of one weight-matrix image (linear 69632B copy) ----
  auto stage_w = [&](int mat) {
    const char* src = (const char*)wsW + (size_t)mat * MAT_B;
    char* dst = smem + OFF_SLAB;
#if __has_builtin(__builtin_amdgcn_global_load_lds)
    typedef const __attribute__((address_space(1))) unsigned int GU32;
    typedef __attribute__((address_space(3))) unsigned int LU32;
#pragma unroll
    for (int it = 0; it < 8; ++it) {
      int off = (it * 512 + t) * 16;
      __builtin_amdgcn_global_load_lds((GU32*)(src + off), (LU32*)(dst + off), 16, 0, 0);
    }
    if (t < 256) {
      int off = (4096 + t) * 16;
      __builtin_amdgcn_global_load_lds((GU32*)(src + off), (LU32*)(dst + off), 16, 0, 0);
    }
#else
#pragma unroll
    for (int it = 0; it < 8; ++it) {
      int off = (it * 512 + t) * 16;
      *(uint4*)(dst + off) = *(const uint4*)(src + off);
    }
    if (t < 256) {
      int off = (4096 + t) * 16;
      *(uint4*)(dst + off) = *(const uint4*)(src + off);
    }
#endif
  };

  // ---- init: constants, x, first slab (W2) ----
  if (t < 128) {
    f32x4 v; v.x = w1[t]; v.y = w1[128 + t]; v.z = b1[t]; v.w = 0.0f;
    W1C[t] = v;
    B2s[t] = b2[t]; B3s[t] = b3[t]; B4s[t] = b4[t]; W5s[t] = w5[t];
    XB[t] = x0[blk * 128 + t];
  }
  stage_w(0);

  const int lane = t & 63;
  const int wave = t >> 6;
  const int c   = lane & 15;
  const int q   = lane >> 4;
  const int wr  = wave & 3;      // row-tile pair: rows 32*wr .. 32*wr+31
  const int wsc = wave >> 2;     // col pair: samples 32*wsc .. 32*wsc+31

  // noise prefetch (one step ahead)
  size_t nbase = (size_t)blk * MBLK * 2 + (t & 127);
  float nz = (t < 128) ? noise[nbase] : 0.0f;

  __syncthreads();

  f32x4 acc[4];                   // [a*2+b]
  f32x4 D1[4], D2[4], D3[4];      // silu' in fp32 regs

#define ACC3(ti, Ah, Al, Bh, Bl)                                               \
  acc[ti] = __builtin_amdgcn_mfma_f32_16x16x32_bf16(Ah.v, Bh.v, acc[ti],0,0,0);\
  acc[ti] = __builtin_amdgcn_mfma_f32_16x16x32_bf16(Ah.v, Bl.v, acc[ti],0,0,0);\
  acc[ti] = __builtin_amdgcn_mfma_f32_16x16x32_bf16(Al.v, Bh.v, acc[ti],0,0,0);

  auto gemm = [&](bool bwd) {
#pragma unroll
    for (int i = 0; i < 4; ++i) acc[i] = (f32x4){0.f, 0.f, 0.f, 0.f};
#pragma unroll
    for (int kk = 0; kk < 4; ++kk) {
      FragU Bh[2], Bl[2];
#pragma unroll
      for (int b = 0; b < 2; ++b) {
        int off = (32 * wsc + 16 * b + c) * PITW + kk * 32 + q * 8;
        Bh[b].v = *(const bf16x8*)(ACTH + off);
        Bl[b].v = *(const bf16x8*)(ACTH + off + APLANE);
      }
#pragma unroll
      for (int a = 0; a < 2; ++a) {
        FragU Ah, Al;
        if (!bwd) {
          int o  = 32 * wr + 16 * a + c;
          int i0 = (kk * 32 + q * 8) ^ (((o >> 3) & 3) << 4);
          const uint16_t* p = SLABH + o * PITW + i0;
          Ah.v = *(const bf16x8*)p;
          Al.v = *(const bf16x8*)(p + WPLANE);
        } else {
          int icol = 32 * wr + 16 * a + c;
          int i2   = icol ^ (q << 4);              // swz(o)=16*((o>>3)&3)=16*q here
          const uint16_t* p = SLABH + (kk * 32 + q * 8) * PITW + i2;
#pragma unroll
          for (int j = 0; j < 8; ++j) {
            Ah.h[j] = p[j * PITW];
            Al.h[j] = p[j * PITW + WPLANE];
          }
        }
        ACC3(a * 2 + 0, Ah, Al, Bh[0], Bl[0])
        ACC3(a * 2 + 1, Ah, Al, Bh[1], Bl[1])
      }
    }
  };

  auto storeAct = [&](int ms, int n0, f32x4 v) {
    uint32_t wh0 = packhi(v[0], v[1]);
    uint32_t wh1 = packhi(v[2], v[3]);
    float l0 = v[0] - cutf(v[0]), l1 = v[1] - cutf(v[1]);
    float l2 = v[2] - cutf(v[2]), l3 = v[3] - cutf(v[3]);
    uint32_t wl0 = packhi(l0, l1);
    uint32_t wl1 = packhi(l2, l3);
    uint16_t* base = ACTH + ms * PITW + n0;
    *(uint2*)base = make_uint2(wh0, wh1);
    *(uint2*)(base + APLANE) = make_uint2(wl0, wl1);
  };

  auto ep_fwd = [&](const float* Bs, f32x4 (&D)[4]) {
#pragma unroll
    for (int a = 0; a < 2; ++a) {
      int n0 = 32 * wr + 16 * a + 4 * q;
      f32x4 bv = *(const f32x4*)(Bs + n0);
#pragma unroll
      for (int b = 0; b < 2; ++b) {
        int ti = a * 2 + b;
        int ms = 32 * wsc + 16 * b + c;
        f32x4 h;
#pragma unroll
        for (int r = 0; r < 4; ++r) {
          float z = acc[ti][r] + bv[r];
          float s = fsigm(z);
          float hh = z * s;
          D[ti][r] = s * (1.0f + z - hh);
          h[r] = hh;
        }
        storeAct(ms, n0, h);
      }
    }
  };

  auto ep_v4 = [&]() {
#pragma unroll
    for (int a = 0; a < 2; ++a) {
      int n0 = 32 * wr + 16 * a + 4 * q;
      f32x4 bv = *(const f32x4*)(B4s + n0);
      f32x4 wv = *(const f32x4*)(W5s + n0);
#pragma unroll
      for (int b = 0; b < 2; ++b) {
        int ti = a * 2 + b;
        int ms = 32 * wsc + 16 * b + c;
        f32x4 v;
#pragma unroll
        for (int r = 0; r < 4; ++r) {
          float z = acc[ti][r] + bv[r];
          float s = fsigm(z);
          float d = s * (1.0f + z - z * s);
          v[r] = wv[r] * d;
        }
        storeAct(ms, n0, v);
      }
    }
  };

  auto ep_bwd = [&](f32x4 (&D)[4]) {
#pragma unroll
    for (int a = 0; a < 2; ++a) {
      int n0 = 32 * wr + 16 * a + 4 * q;
#pragma unroll
      for (int b = 0; b < 2; ++b) {
        int ti = a * 2 + b;
        int ms = 32 * wsc + 16 * b + c;
        f32x4 v;
#pragma unroll
        for (int r = 0; r < 4; ++r) v[r] = acc[ti][r] * D[ti][r];
        storeAct(ms, n0, v);
      }
    }
  };

  auto ep_bwd1 = [&]() {
#pragma unroll
    for (int a = 0; a < 2; ++a) {
      int n0 = 32 * wr + 16 * a + 4 * q;
#pragma unroll
      for (int b = 0; b < 2; ++b) {
        int ti = a * 2 + b;
        int ms = 32 * wsc + 16 * b + c;
        f32x4 v;
#pragma unroll
        for (int r = 0; r < 4; ++r) v[r] = acc[ti][r] * D1[ti][r];
        *(f32x4*)(V1F + ms * 132 + n0) = v;
      }
    }
  };

  auto l1_phase = [&]() {
    f32x4 wv[2][4];
#pragma unroll
    for (int a = 0; a < 2; ++a)
#pragma unroll
      for (int r = 0; r < 4; ++r) wv[a][r] = W1C[32 * wr + 16 * a + 4 * q + r];
#pragma unroll
    for (int b = 0; b < 2; ++b) {
      int ms = 32 * wsc + 16 * b + c;
      float xa = XB[2 * ms], xb = XB[2 * ms + 1];
#pragma unroll
      for (int a = 0; a < 2; ++a) {
        int ti = a * 2 + b;
        int n0 = 32 * wr + 16 * a + 4 * q;
        f32x4 h;
#pragma unroll
        for (int r = 0; r < 4; ++r) {
          float z = fmaf(xa, wv[a][r].x, fmaf(xb, wv[a][r].y, wv[a][r].z));
          float s = fsigm(z);
          float hh = z * s;
          D1[ti][r] = s * (1.0f + z - hh);
          h[r] = hh;
        }
        storeAct(ms, n0, h);
      }
    }
  };

  auto g_phase = [&](int step) {
    if (t < 128) {
      int s = t >> 1, p = t & 1;
      float g0 = 0.f, g1 = 0.f;
      const f32x4* vp = (const f32x4*)(V1F + s * 132 + 64 * p);
#pragma unroll
      for (int i = 0; i < 16; ++i) {
        f32x4 v = vp[i];
        int n = 64 * p + 4 * i;
#pragma unroll
        for (int r = 0; r < 4; ++r) {
          f32x4 wvv = W1C[n + r];
          g0 = fmaf(v[r], wvv.x, g0);
          g1 = fmaf(v[r], wvv.y, g1);
        }
      }
      g0 += __shfl_xor(g0, 1);
      g1 += __shfl_xor(g1, 1);
      float g = p ? g1 : g0;
      g = fminf(fmaxf(g, -0.03f), 0.03f);
      float epsv = 10.0f * (1.0f - (float)step / 60.0f);
      float xn = XB[t] + sqrtf(2.0f * epsv) * nz * 0.005f + epsv * g;
      xn = fminf(fmaxf(xn, -2.43f), 3.05f);
      XB[t] = xn;
      if (step == NSTEP - 1) {
        out[(size_t)blk * 128 + t] = xn;
      } else {
        nz = noise[(size_t)(step + 1) * NTOT * 2 + nbase];   // prefetch next step
      }
    }
  };

#pragma unroll 1
  for (int step = 0; step < NSTEP; ++step) {
    l1_phase();               __syncthreads();
    gemm(false);              __syncthreads();   // z2 (slab=W2)
    stage_w(1); ep_fwd(B2s, D2); __syncthreads();
    gemm(false);              __syncthreads();   // z3 (slab=W3)
    stage_w(2); ep_fwd(B3s, D3); __syncthreads();
    gemm(false);              __syncthreads();   // z4 (slab=W4)
    ep_v4();                  __syncthreads();
    gemm(true);               __syncthreads();   // u3 = v4 @ W4^T
    stage_w(1); ep_bwd(D3);   __syncthreads();
    gemm(true);               __syncthreads();   // u2 = v3 @ W3^T
    stage_w(0); ep_bwd(D2);   __syncthreads();
    gemm(true);               __syncthreads();   // u1 = v2 @ W2^T
    ep_bwd1();                __syncthreads();   // v1 fp32
    g_phase(step);            __syncthreads();   // slab=W2 for next step
  }
}

extern "C" void kernel_launch(void* const* d_in, const int* in_sizes, int n_in,
                              void* d_out, int out_size, void* d_ws, size_t ws_size,
                              hipStream_t stream) {
  // inputs: x0,w1,b1,w2,b2,w3,b3,w4,b4,w5,b5,noise
  (void)in_sizes; (void)n_in; (void)out_size; (void)ws_size;
  hipFuncSetAttribute((const void*)ebm_mcmc_kernel,
                      hipFuncAttributeMaxDynamicSharedMemorySize, LDS_TOTAL);
  ebm_prep_kernel<<<3, 512, 0, stream>>>(
      (const float*)d_in[3], (const float*)d_in[5], (const float*)d_in[7],
      (uint16_t*)d_ws);
  ebm_mcmc_kernel<<<NTOT / MBLK, 512, LDS_TOTAL, stream>>>(
      (const float*)d_in[0], (const float*)d_in[1], (const float*)d_in[2],
      (const float*)d_in[4], (const float*)d_in[6], (const float*)d_in[8],
      (const float*)d_in[9], (const float*)d_in[11], (const uint16_t*)d_ws,
      (float*)d_out);
}

// Round 4
// 7637.088 us; speedup vs baseline: 3.1240x; 1.1181x over previous
//
#include <hip/hip_runtime.h>
#include <stdint.h>

#define NTOT   131072
#define NSTEP  60
#define MBLK   64
#define PITW   136            // halves per ACT row
#define APLANE 8704           // halves per ACT plane (64*136)
#define IMG_H  32768          // halves per W image (hi 16384 + lo 16384)
#define IMG_B  65536          // bytes per W image
#define PLANE_H 16384         // halves per W plane

// LDS byte offsets
#define OFF_SLAB 0            // 65536
#define OFF_ACTH 65536        // hi 17408 + lo 17408
#define OFF_GP   100352       // 4*64*2*4 = 2048
#define OFF_W1C  102400       // 2048
#define OFF_B2   104448
#define OFF_B3   104960
#define OFF_B4   105472
#define OFF_W5   105984
#define OFF_XB   106496       // 512
#define LDS_TOTAL 107008

typedef float  f32x4  __attribute__((ext_vector_type(4)));
typedef short  bf16x8 __attribute__((ext_vector_type(8)));
union FragU { bf16x8 v; uint32_t u[4]; uint16_t h[8]; };

static __device__ __forceinline__ uint32_t rne_bits(float f) {
  uint32_t u = __float_as_uint(f);
  return u + 0x7fffu + ((u >> 16) & 1u);   // high16 = rne bf16
}
static __device__ __forceinline__ float fsigm(float z) {
  return __builtin_amdgcn_rcpf(1.0f + __builtin_amdgcn_exp2f(z * -1.44269504089f));
}
// pack rne-bf16(a) | rne-bf16(b)<<16 from pre-biased bit patterns
static __device__ __forceinline__ uint32_t packbits(uint32_t ta, uint32_t tb) {
  return __builtin_amdgcn_perm(tb, ta, 0x07060302u);
}

// ---- prep: 6 fragment-order split-bf16 W images in d_ws ----
// img 0..2: forward (A row = output o), of w2,w3,w4
// img 3..5: backward (A row = input  i), of w4,w3,w2
extern "C" __global__ void ebm_prep_kernel(const float* __restrict__ w2,
                                           const float* __restrict__ w3,
                                           const float* __restrict__ w4,
                                           uint16_t* __restrict__ ws) {
  int img = blockIdx.x;
  const float* w = (img == 0 || img == 5) ? w2 : (img == 1 || img == 4) ? w3 : w2;
  if (img == 2 || img == 3) w = w4;
  uint16_t* hiP = ws + (size_t)img * IMG_H;
  uint16_t* loP = hiP + PLANE_H;
  for (int e = threadIdx.x; e < 16384; e += blockDim.x) {
    int i = e >> 7, o = e & 127;          // w[i][o], i=input, o=output
    int row = (img < 3) ? o : i;          // A-row index m
    int k   = (img < 3) ? i : o;          // A-col index k
    int rb = row >> 4, c = row & 15;
    int kk = k >> 5, q = (k >> 3) & 3, j = k & 7;
    int off = ((rb * 4 + kk) * 64 + q * 16 + c) * 8 + j;
    float v = w[e];
    uint32_t t = rne_bits(v);
    float lo = v - __uint_as_float(t & 0xffff0000u);
    hiP[off] = (uint16_t)(t >> 16);
    loP[off] = (uint16_t)(rne_bits(lo) >> 16);
  }
}

extern "C" __global__ void __launch_bounds__(512, 2)
ebm_mcmc_kernel(const float* __restrict__ x0, const float* __restrict__ w1,
                const float* __restrict__ b1, const float* __restrict__ b2,
                const float* __restrict__ b3, const float* __restrict__ b4,
                const float* __restrict__ w5, const float* __restrict__ noise,
                const uint16_t* __restrict__ wsW, float* __restrict__ out)
{
  extern __shared__ char smem[];
  uint16_t* SLABH = (uint16_t*)(smem + OFF_SLAB);   // frag-order, lo at +PLANE_H
  uint16_t* ACTH  = (uint16_t*)(smem + OFF_ACTH);   // row-major, lo at +APLANE
  float*    GPf   = (float*)(smem + OFF_GP);        // [wr][64 samples][2]
  f32x4*    W1C   = (f32x4*)(smem + OFF_W1C);       // (w1[0][n], w1[1][n], b1[n], 0)
  float*    B2s   = (float*)(smem + OFF_B2);
  float*    B3s   = (float*)(smem + OFF_B3);
  float*    B4s   = (float*)(smem + OFF_B4);
  float*    W5s   = (float*)(smem + OFF_W5);
  float*    XB    = (float*)(smem + OFF_XB);

  const int t   = threadIdx.x;
  const int blk = blockIdx.x;

  // ---- async linear restage of one 64KB W image ----
  auto stage_w = [&](int img) {
    const char* src = (const char*)wsW + (size_t)img * IMG_B;
    char* dst = smem + OFF_SLAB;
    typedef const __attribute__((address_space(1))) unsigned int GU32;
    typedef __attribute__((address_space(3))) unsigned int LU32;
#pragma unroll
    for (int it = 0; it < 8; ++it) {
      int off = (it * 512 + t) * 16;
      __builtin_amdgcn_global_load_lds((GU32*)(src + off), (LU32*)(dst + off), 16, 0, 0);
    }
  };

  if (t < 128) {
    f32x4 v; v.x = w1[t]; v.y = w1[128 + t]; v.z = b1[t]; v.w = 0.0f;
    W1C[t] = v;
    B2s[t] = b2[t]; B3s[t] = b3[t]; B4s[t] = b4[t]; W5s[t] = w5[t];
    XB[t] = x0[blk * 128 + t];
  }
  stage_w(0);

  const int lane = t & 63;
  const int wave = t >> 6;
  const int c   = lane & 15;
  const int q   = lane >> 4;
  const int wr  = wave & 3;       // hidden rows 32*wr..+31
  const int wsc = wave >> 2;      // samples 32*wsc..+31

  size_t nbase = (size_t)blk * 128 + (t & 127);
  float nz = (t < 128) ? noise[nbase] : 0.0f;

  __syncthreads();

  // W1 rows for this wave's hidden indices, hoisted to registers (step-invariant)
  f32x4 wreg[2][4];
#pragma unroll
  for (int a = 0; a < 2; ++a)
#pragma unroll
    for (int r = 0; r < 4; ++r) wreg[a][r] = W1C[32 * wr + 16 * a + 4 * q + r];

  f32x4 acc[4], accx[4];
  f32x4 D1[4], D2[4], D3[4];

  auto gemm = [&]() {
#pragma unroll
    for (int i = 0; i < 4; ++i) { acc[i] = (f32x4){0.f,0.f,0.f,0.f}; accx[i] = acc[i]; }
#pragma unroll
    for (int kk = 0; kk < 4; ++kk) {
      FragU Bh[2], Bl[2];
#pragma unroll
      for (int b = 0; b < 2; ++b) {
        int off = (32 * wsc + 16 * b + c) * PITW + kk * 32 + q * 8;
        Bh[b].v = *(const bf16x8*)(ACTH + off);
        Bl[b].v = *(const bf16x8*)(ACTH + off + APLANE);
      }
#pragma unroll
      for (int a = 0; a < 2; ++a) {
        int fo = (((2 * wr + a) * 4 + kk) * 64 + lane) * 8;   // linear frag read
        FragU Ah, Al;
        Ah.v = *(const bf16x8*)(SLABH + fo);
        Al.v = *(const bf16x8*)(SLABH + fo + PLANE_H);
#pragma unroll
        for (int b = 0; b < 2; ++b) {
          int ti = a * 2 + b;
          acc[ti]  = __builtin_amdgcn_mfma_f32_16x16x32_bf16(Ah.v, Bh[b].v, acc[ti], 0,0,0);
          accx[ti] = __builtin_amdgcn_mfma_f32_16x16x32_bf16(Ah.v, Bl[b].v, accx[ti],0,0,0);
          accx[ti] = __builtin_amdgcn_mfma_f32_16x16x32_bf16(Al.v, Bh[b].v, accx[ti],0,0,0);
        }
      }
    }
#pragma unroll
    for (int i = 0; i < 4; ++i) acc[i] += accx[i];
  };

  auto storeAct = [&](int ms, int n0, f32x4 v) {
    uint32_t tb[4]; f32x4 lo;
#pragma unroll
    for (int r = 0; r < 4; ++r) {
      tb[r] = rne_bits(v[r]);
      lo[r] = v[r] - __uint_as_float(tb[r] & 0xffff0000u);
    }
    uint16_t* base = ACTH + ms * PITW + n0;
    *(uint2*)base = make_uint2(packbits(tb[0], tb[1]), packbits(tb[2], tb[3]));
    *(uint2*)(base + APLANE) =
        make_uint2(packbits(rne_bits(lo[0]), rne_bits(lo[1])),
                   packbits(rne_bits(lo[2]), rne_bits(lo[3])));
  };

  auto ep_fwd = [&](const float* Bs, f32x4 (&D)[4]) {
#pragma unroll
    for (int a = 0; a < 2; ++a) {
      int n0 = 32 * wr + 16 * a + 4 * q;
      f32x4 bv = *(const f32x4*)(Bs + n0);
#pragma unroll
      for (int b = 0; b < 2; ++b) {
        int ti = a * 2 + b, ms = 32 * wsc + 16 * b + c;
        f32x4 h;
#pragma unroll
        for (int r = 0; r < 4; ++r) {
          float z = acc[ti][r] + bv[r];
          float s = fsigm(z);
          float hh = z * s;
          D[ti][r] = s * (1.0f + z - hh);
          h[r] = hh;
        }
        storeAct(ms, n0, h);
      }
    }
  };

  auto ep_v4 = [&]() {
#pragma unroll
    for (int a = 0; a < 2; ++a) {
      int n0 = 32 * wr + 16 * a + 4 * q;
      f32x4 bv = *(const f32x4*)(B4s + n0);
      f32x4 wv = *(const f32x4*)(W5s + n0);
#pragma unroll
      for (int b = 0; b < 2; ++b) {
        int ti = a * 2 + b, ms = 32 * wsc + 16 * b + c;
        f32x4 v;
#pragma unroll
        for (int r = 0; r < 4; ++r) {
          float z = acc[ti][r] + bv[r];
          float s = fsigm(z);
          v[r] = wv[r] * (s * (1.0f + z - z * s));
        }
        storeAct(ms, n0, v);
      }
    }
  };

  auto ep_bwd = [&](f32x4 (&D)[4]) {
#pragma unroll
    for (int a = 0; a < 2; ++a) {
      int n0 = 32 * wr + 16 * a + 4 * q;
#pragma unroll
      for (int b = 0; b < 2; ++b) {
        int ti = a * 2 + b, ms = 32 * wsc + 16 * b + c;
        f32x4 v;
#pragma unroll
        for (int r = 0; r < 4; ++r) v[r] = acc[ti][r] * D[ti][r];
        storeAct(ms, n0, v);
      }
    }
  };

  // u1-epilogue: v1 = acc.*D1 ; partial g per sample via in-register contraction
  auto ep_bwd1 = [&]() {
#pragma unroll
    for (int b = 0; b < 2; ++b) {
      float gx = 0.f, gy = 0.f;
#pragma unroll
      for (int a = 0; a < 2; ++a) {
        int ti = a * 2 + b;
#pragma unroll
        for (int r = 0; r < 4; ++r) {
          float v = acc[ti][r] * D1[ti][r];
          gx = fmaf(v, wreg[a][r].x, gx);
          gy = fmaf(v, wreg[a][r].y, gy);
        }
      }
      gx += __shfl_xor(gx, 16); gx += __shfl_xor(gx, 32);
      gy += __shfl_xor(gy, 16); gy += __shfl_xor(gy, 32);
      if (q == 0) {
        int s = 32 * wsc + 16 * b + c;
        *(float2*)(GPf + (wr * 64 + s) * 2) = make_float2(gx, gy);
      }
    }
  };

  auto l1_phase = [&]() {
#pragma unroll
    for (int b = 0; b < 2; ++b) {
      int ms = 32 * wsc + 16 * b + c;
      float xa = XB[2 * ms], xb = XB[2 * ms + 1];
#pragma unroll
      for (int a = 0; a < 2; ++a) {
        int ti = a * 2 + b;
        int n0 = 32 * wr + 16 * a + 4 * q;
        f32x4 h;
#pragma unroll
        for (int r = 0; r < 4; ++r) {
          float z = fmaf(xa, wreg[a][r].x, fmaf(xb, wreg[a][r].y, wreg[a][r].z));
          float s = fsigm(z);
          float hh = z * s;
          D1[ti][r] = s * (1.0f + z - hh);
          h[r] = hh;
        }
        storeAct(ms, n0, h);
      }
    }
  };

  auto g_finish = [&](int step) {
    if (t < 128) {
      int s = t >> 1, p = t & 1;
      float g = GPf[s * 2 + p] + GPf[128 + s * 2 + p] +
                GPf[256 + s * 2 + p] + GPf[384 + s * 2 + p];
      g = fminf(fmaxf(g, -0.03f), 0.03f);
      float epsv = 10.0f * (1.0f - (float)step / 60.0f);
      float xn = XB[t] + sqrtf(2.0f * epsv) * nz * 0.005f + epsv * g;
      xn = fminf(fmaxf(xn, -2.43f), 3.05f);
      XB[t] = xn;
      if (step == NSTEP - 1) {
        out[(size_t)blk * 128 + t] = xn;
      } else {
        nz = noise[(size_t)(step + 1) * NTOT * 2 + nbase];
      }
    }
  };

#pragma unroll 1
  for (int step = 0; step < NSTEP; ++step) {
    l1_phase();                  __syncthreads();
    gemm();                      __syncthreads();   // z2 (slab=W2^T)
    stage_w(1); ep_fwd(B2s, D2); __syncthreads();
    gemm();                      __syncthreads();   // z3 (slab=W3^T)
    stage_w(2); ep_fwd(B3s, D3); __syncthreads();
    gemm();                      __syncthreads();   // z4 (slab=W4^T)
    stage_w(3); ep_v4();         __syncthreads();
    gemm();                      __syncthreads();   // u3 (slab=W4 nat)
    stage_w(4); ep_bwd(D3);      __syncthreads();
    gemm();                      __syncthreads();   // u2 (slab=W3 nat)
    stage_w(5); ep_bwd(D2);      __syncthreads();
    gemm();                      __syncthreads();   // u1 (slab=W2 nat)
    stage_w(0); ep_bwd1();       __syncthreads();   // partial g -> GP, restage W2^T
    g_finish(step);              __syncthreads();
  }
}

extern "C" void kernel_launch(void* const* d_in, const int* in_sizes, int n_in,
                              void* d_out, int out_size, void* d_ws, size_t ws_size,
                              hipStream_t stream) {
  // inputs: x0,w1,b1,w2,b2,w3,b3,w4,b4,w5,b5,noise
  (void)in_sizes; (void)n_in; (void)out_size; (void)ws_size;
  hipFuncSetAttribute((const void*)ebm_mcmc_kernel,
                      hipFuncAttributeMaxDynamicSharedMemorySize, LDS_TOTAL);
  ebm_prep_kernel<<<6, 256, 0, stream>>>(
      (const float*)d_in[3], (const float*)d_in[5], (const float*)d_in[7],
      (uint16_t*)d_ws);
  ebm_mcmc_kernel<<<NTOT / MBLK, 512, LDS_TOTAL, stream>>>(
      (const float*)d_in[0], (const float*)d_in[1], (const float*)d_in[2],
      (const float*)d_in[4], (const float*)d_in[6], (const float*)d_in[8],
      (const float*)d_in[9], (const float*)d_in[11], (const uint16_t*)d_ws,
      (float*)d_out);
}

// Round 5
// 7339.729 us; speedup vs baseline: 3.2506x; 1.0405x over previous
//
#include <hip/hip_runtime.h>
#include <stdint.h>

#define NTOT    131072
#define NSTEP   60
#define MBLK    128
#define PLANE_H 16384          // halves per fragment plane (32 groups * 64 slots * 8)
#define IMG_H   32768          // halves per image (hi + lo plane)
#define IMG_B   65536          // bytes per image

// LDS byte offsets
#define OFF_SLAB 0             // 65536: W image (frag order, hi + lo)
#define OFF_ACT  65536         // 65536: ACT image (frag order, hi + lo)
#define OFF_GP   131072        // 4*128*2*4 = 4096
#define OFF_W1C  135168        // 2048
#define OFF_B2   137216        // 512
#define OFF_B3   137728
#define OFF_B4   138240
#define OFF_W5   138752
#define OFF_XB   139264        // 256*4 = 1024
#define LDS_TOTAL 140288

typedef float  f32x4  __attribute__((ext_vector_type(4)));
typedef float  f32x16 __attribute__((ext_vector_type(16)));
typedef short  bf16x8 __attribute__((ext_vector_type(8)));
union FragU { bf16x8 v; uint32_t u[4]; uint16_t h[8]; };

static __device__ __forceinline__ uint32_t rne_bits(float f) {
  uint32_t u = __float_as_uint(f);
  return u + 0x7fffu + ((u >> 16) & 1u);   // high16 = rne bf16
}
static __device__ __forceinline__ float fsigm(float z) {
  return __builtin_amdgcn_rcpf(1.0f + __builtin_amdgcn_exp2f(z * -1.44269504089f));
}
static __device__ __forceinline__ uint32_t packbits(uint32_t ta, uint32_t tb) {
  return __builtin_amdgcn_perm(tb, ta, 0x07060302u);   // bf16(a) | bf16(b)<<16
}

// ---- prep: 6 fragment-order (32x32x16 A-layout) split-bf16 W images ----
// img 0..2: forward A = W^T of w2,w3,w4 (m=out, k=in)
// img 3..5: backward A = W natural of w4,w3,w2 (m=in, k=out)
extern "C" __global__ void ebm_prep_kernel(const float* __restrict__ w2,
                                           const float* __restrict__ w3,
                                           const float* __restrict__ w4,
                                           uint16_t* __restrict__ ws) {
  int img = blockIdx.x;
  bool bwd = img >= 3;
  int li = bwd ? 5 - img : img;
  const float* w = (li == 0) ? w2 : (li == 1) ? w3 : w4;
  uint16_t* hiP = ws + (size_t)img * IMG_H;
  uint16_t* loP = hiP + PLANE_H;
  for (int e = threadIdx.x; e < 16384; e += blockDim.x) {
    int i = e >> 7, o = e & 127;            // w[i][o]
    int m = bwd ? i : o;
    int k = bwd ? o : i;
    int slot = ((m >> 5) * 8 + (k >> 4)) * 64 + (m & 31) + 32 * ((k >> 3) & 1);
    int off = slot * 8 + (k & 7);
    float v = w[e];
    uint32_t tb = rne_bits(v);
    float lo = v - __uint_as_float(tb & 0xffff0000u);
    hiP[off] = (uint16_t)(tb >> 16);
    loP[off] = (uint16_t)(rne_bits(lo) >> 16);
  }
}

extern "C" __global__ void __launch_bounds__(512, 2)
ebm_mcmc_kernel(const float* __restrict__ x0, const float* __restrict__ w1,
                const float* __restrict__ b1, const float* __restrict__ b2,
                const float* __restrict__ b3, const float* __restrict__ b4,
                const float* __restrict__ w5, const float* __restrict__ noise,
                const uint16_t* __restrict__ wsW, float* __restrict__ out)
{
  extern __shared__ char smem[];
  uint16_t* SLABH = (uint16_t*)(smem + OFF_SLAB);   // W frag image, lo at +PLANE_H
  uint16_t* ACTH  = (uint16_t*)(smem + OFF_ACT);    // ACT frag image, lo at +PLANE_H
  float*    GPf   = (float*)(smem + OFF_GP);        // [wr][128 samples][2]
  f32x4*    W1C   = (f32x4*)(smem + OFF_W1C);       // (w1[0][n], w1[1][n], b1[n], 0)
  float*    B2s   = (float*)(smem + OFF_B2);
  float*    B3s   = (float*)(smem + OFF_B3);
  float*    B4s   = (float*)(smem + OFF_B4);
  float*    W5s   = (float*)(smem + OFF_W5);
  float*    XB    = (float*)(smem + OFF_XB);        // x state fp32 [128][2]

  const int t   = threadIdx.x;
  const int blk = blockIdx.x;

  auto stage_w = [&](int img) {
    const char* src = (const char*)wsW + (size_t)img * IMG_B;
    char* dst = smem + OFF_SLAB;
    typedef const __attribute__((address_space(1))) unsigned int GU32;
    typedef __attribute__((address_space(3))) unsigned int LU32;
#pragma unroll
    for (int it = 0; it < 8; ++it) {
      int off = (it * 512 + t) * 16;
      __builtin_amdgcn_global_load_lds((GU32*)(src + off), (LU32*)(dst + off), 16, 0, 0);
    }
  };

  if (t < 128) {
    f32x4 v; v.x = w1[t]; v.y = w1[128 + t]; v.z = b1[t]; v.w = 0.0f;
    W1C[t] = v;
    B2s[t] = b2[t]; B3s[t] = b3[t]; B4s[t] = b4[t]; W5s[t] = w5[t];
  }
  if (t < 256) XB[t] = x0[blk * 256 + t];
  stage_w(0);

  const int lane = t & 63;
  const int wave = t >> 6;
  const int c32 = lane & 31;      // sample within 32-tile / A-row m
  const int h   = lane >> 5;      // lane half (k-half of frags; row offset 4h in C)
  const int wr  = wave & 3;       // hidden rows 32*wr..+31
  const int wsh = wave >> 2;      // sample half: samples 64*wsh..+63

  size_t nbase = (size_t)blk * 256 + (t & 255);
  float nz = (t < 256) ? noise[nbase] : 0.0f;

  __syncthreads();

  f32x16 acc[2];                  // [sample tile b], 16 regs each
  float D1[32], D2[32], D3[32];   // silu' fp32, [b*16 + r]

  auto gemm = [&]() {
    acc[0] = (f32x16)0.0f; acc[1] = (f32x16)0.0f;
#pragma unroll
    for (int ks = 0; ks < 8; ++ks) {
      const uint16_t* ap = SLABH + ((wr * 8 + ks) * 64 + lane) * 8;
      FragU Ah, Al;
      Ah.v = *(const bf16x8*)ap;
      Al.v = *(const bf16x8*)(ap + PLANE_H);
      const uint16_t* bp0 = ACTH + (((2 * wsh + 0) * 8 + ks) * 64 + lane) * 8;
      const uint16_t* bp1 = ACTH + (((2 * wsh + 1) * 8 + ks) * 64 + lane) * 8;
      FragU B0h, B0l, B1h, B1l;
      B0h.v = *(const bf16x8*)bp0;  B0l.v = *(const bf16x8*)(bp0 + PLANE_H);
      B1h.v = *(const bf16x8*)bp1;  B1l.v = *(const bf16x8*)(bp1 + PLANE_H);
      acc[0] = __builtin_amdgcn_mfma_f32_32x32x16_bf16(Ah.v, B0h.v, acc[0], 0, 0, 0);
      acc[1] = __builtin_amdgcn_mfma_f32_32x32x16_bf16(Ah.v, B1h.v, acc[1], 0, 0, 0);
      acc[0] = __builtin_amdgcn_mfma_f32_32x32x16_bf16(Ah.v, B0l.v, acc[0], 0, 0, 0);
      acc[1] = __builtin_amdgcn_mfma_f32_32x32x16_bf16(Ah.v, B1l.v, acc[1], 0, 0, 0);
      acc[0] = __builtin_amdgcn_mfma_f32_32x32x16_bf16(Al.v, B0h.v, acc[0], 0, 0, 0);
      acc[1] = __builtin_amdgcn_mfma_f32_32x32x16_bf16(Al.v, B1h.v, acc[1], 0, 0, 0);
    }
  };

  // C element (b, t, rr) -> B-frag image: k = 32wr+8t+4h+rr, n = 64wsh+32b+c32
  auto storeAct = [&](int b, int tt, f32x4 v) {
    uint32_t tb0 = rne_bits(v[0]), tb1 = rne_bits(v[1]);
    uint32_t tb2 = rne_bits(v[2]), tb3 = rne_bits(v[3]);
    float l0 = v[0] - __uint_as_float(tb0 & 0xffff0000u);
    float l1 = v[1] - __uint_as_float(tb1 & 0xffff0000u);
    float l2 = v[2] - __uint_as_float(tb2 & 0xffff0000u);
    float l3 = v[3] - __uint_as_float(tb3 & 0xffff0000u);
    int slot = ((2 * wsh + b) * 8 + 2 * wr + (tt >> 1)) * 64 + c32 + 32 * (tt & 1);
    uint16_t* p = ACTH + slot * 8 + 4 * h;
    *(uint2*)p = make_uint2(packbits(tb0, tb1), packbits(tb2, tb3));
    *(uint2*)(p + PLANE_H) =
        make_uint2(packbits(rne_bits(l0), rne_bits(l1)),
                   packbits(rne_bits(l2), rne_bits(l3)));
  };

  auto ep_fwd = [&](const float* Bs, float* D) {
#pragma unroll
    for (int tt = 0; tt < 4; ++tt) {
      f32x4 bv = *(const f32x4*)(Bs + 32 * wr + 8 * tt + 4 * h);
#pragma unroll
      for (int b = 0; b < 2; ++b) {
        f32x4 hv;
#pragma unroll
        for (int rr = 0; rr < 4; ++rr) {
          float z = acc[b][4 * tt + rr] + bv[rr];
          float s = fsigm(z);
          float hh = z * s;
          D[b * 16 + 4 * tt + rr] = s * (1.0f + z - hh);
          hv[rr] = hh;
        }
        storeAct(b, tt, hv);
      }
    }
  };

  auto ep_v4 = [&]() {
#pragma unroll
    for (int tt = 0; tt < 4; ++tt) {
      f32x4 bv = *(const f32x4*)(B4s + 32 * wr + 8 * tt + 4 * h);
      f32x4 wv = *(const f32x4*)(W5s + 32 * wr + 8 * tt + 4 * h);
#pragma unroll
      for (int b = 0; b < 2; ++b) {
        f32x4 vv;
#pragma unroll
        for (int rr = 0; rr < 4; ++rr) {
          float z = acc[b][4 * tt + rr] + bv[rr];
          float s = fsigm(z);
          vv[rr] = wv[rr] * (s * (1.0f + z - z * s));
        }
        storeAct(b, tt, vv);
      }
    }
  };

  auto ep_bwd = [&](float* D) {
#pragma unroll
    for (int tt = 0; tt < 4; ++tt)
#pragma unroll
      for (int b = 0; b < 2; ++b) {
        f32x4 vv;
#pragma unroll
        for (int rr = 0; rr < 4; ++rr)
          vv[rr] = acc[b][4 * tt + rr] * D[b * 16 + 4 * tt + rr];
        storeAct(b, tt, vv);
      }
  };

  // u1 epilogue: v1 = acc .* D1 ; in-register contraction against w1 -> GP
  auto ep_bwd1 = [&]() {
    float gx[2] = {0.f, 0.f}, gy[2] = {0.f, 0.f};
#pragma unroll
    for (int tt = 0; tt < 4; ++tt) {
      const f32x4* wp = W1C + 32 * wr + 8 * tt + 4 * h;
      f32x4 w0 = wp[0], w1v = wp[1], w2v = wp[2], w3v = wp[3];
#pragma unroll
      for (int b = 0; b < 2; ++b) {
        float v0 = acc[b][4 * tt + 0] * D1[b * 16 + 4 * tt + 0];
        float v1 = acc[b][4 * tt + 1] * D1[b * 16 + 4 * tt + 1];
        float v2 = acc[b][4 * tt + 2] * D1[b * 16 + 4 * tt + 2];
        float v3 = acc[b][4 * tt + 3] * D1[b * 16 + 4 * tt + 3];
        gx[b] = fmaf(v0, w0.x, fmaf(v1, w1v.x, fmaf(v2, w2v.x, fmaf(v3, w3v.x, gx[b]))));
        gy[b] = fmaf(v0, w0.y, fmaf(v1, w1v.y, fmaf(v2, w2v.y, fmaf(v3, w3v.y, gy[b]))));
      }
    }
#pragma unroll
    for (int b = 0; b < 2; ++b) {
      gx[b] += __shfl_xor(gx[b], 32);
      gy[b] += __shfl_xor(gy[b], 32);
      if (h == 0) {
        int s = 64 * wsh + 32 * b + c32;
        *(float2*)(GPf + (wr * 128 + s) * 2) = make_float2(gx[b], gy[b]);
      }
    }
  };

  auto l1_phase = [&]() {
    float2 xv[2];
#pragma unroll
    for (int b = 0; b < 2; ++b)
      xv[b] = *(const float2*)(XB + 2 * (64 * wsh + 32 * b + c32));
#pragma unroll
    for (int tt = 0; tt < 4; ++tt) {
      const f32x4* wp = W1C + 32 * wr + 8 * tt + 4 * h;
      f32x4 wvs0 = wp[0], wvs1 = wp[1], wvs2 = wp[2], wvs3 = wp[3];
#pragma unroll
      for (int b = 0; b < 2; ++b) {
        f32x4 hv;
        f32x4 wv_[4] = {wvs0, wvs1, wvs2, wvs3};
#pragma unroll
        for (int rr = 0; rr < 4; ++rr) {
          float z = fmaf(xv[b].x, wv_[rr].x, fmaf(xv[b].y, wv_[rr].y, wv_[rr].z));
          float s = fsigm(z);
          float hh = z * s;
          D1[b * 16 + 4 * tt + rr] = s * (1.0f + z - hh);
          hv[rr] = hh;
        }
        storeAct(b, tt, hv);
      }
    }
  };

  auto g_finish = [&](int step) {
    if (t < 256) {
      int s = t >> 1, p = t & 1;
      float g = GPf[s * 2 + p] + GPf[256 + s * 2 + p] +
                GPf[512 + s * 2 + p] + GPf[768 + s * 2 + p];
      g = fminf(fmaxf(g, -0.03f), 0.03f);
      float epsv = 10.0f * (1.0f - (float)step / 60.0f);
      float xn = XB[t] + sqrtf(2.0f * epsv) * nz * 0.005f + epsv * g;
      xn = fminf(fmaxf(xn, -2.43f), 3.05f);
      XB[t] = xn;
      if (step == NSTEP - 1) {
        out[(size_t)blk * 256 + t] = xn;
      } else {
        nz = noise[(size_t)(step + 1) * NTOT * 2 + nbase];
      }
    }
  };

#pragma unroll 1
  for (int step = 0; step < NSTEP; ++step) {
    l1_phase();                  __syncthreads();
    gemm();                      __syncthreads();   // z2 (slab = W2^T)
    stage_w(1); ep_fwd(B2s, D2); __syncthreads();
    gemm();                      __syncthreads();   // z3 (slab = W3^T)
    stage_w(2); ep_fwd(B3s, D3); __syncthreads();
    gemm();                      __syncthreads();   // z4 (slab = W4^T)
    stage_w(3); ep_v4();         __syncthreads();
    gemm();                      __syncthreads();   // u3 (slab = W4 nat)
    stage_w(4); ep_bwd(D3);      __syncthreads();
    gemm();                      __syncthreads();   // u2 (slab = W3 nat)
    stage_w(5); ep_bwd(D2);      __syncthreads();
    gemm();                      __syncthreads();   // u1 (slab = W2 nat)
    stage_w(0); ep_bwd1();       __syncthreads();   // g partials, restage W2^T
    g_finish(step);              __syncthreads();
  }
}

extern "C" void kernel_launch(void* const* d_in, const int* in_sizes, int n_in,
                              void* d_out, int out_size, void* d_ws, size_t ws_size,
                              hipStream_t stream) {
  // inputs: x0,w1,b1,w2,b2,w3,b3,w4,b4,w5,b5,noise
  (void)in_sizes; (void)n_in; (void)out_size; (void)ws_size;
  hipFuncSetAttribute((const void*)ebm_mcmc_kernel,
                      hipFuncAttributeMaxDynamicSharedMemorySize, LDS_TOTAL);
  ebm_prep_kernel<<<6, 256, 0, stream>>>(
      (const float*)d_in[3], (const float*)d_in[5], (const float*)d_in[7],
      (uint16_t*)d_ws);
  ebm_mcmc_kernel<<<NTOT / MBLK, 512, LDS_TOTAL, stream>>>(
      (const float*)d_in[0], (const float*)d_in[1], (const float*)d_in[2],
      (const float*)d_in[4], (const float*)d_in[6], (const float*)d_in[8],
      (const float*)d_in[9], (const float*)d_in[11], (const uint16_t*)d_ws,
      (float*)d_out);
}